// Round 2
// baseline (215.426 us; speedup 1.0000x reference)
//
#include <hip/hip_runtime.h>

// Grid: 512x512 nodes, idx = row*512 + col. h = 1/511.
// m_in = [s_dst, deg_dst, s_src, deg_src, ea_x, ea_y] @ W1 -> tanh -> @ W2
// g(s)[n] = (1/deg_n) * sum_incoming(msg) + b2
//
// R1: tanh via Pade[5/4] (exact coefficients, clamp +-3.8, max err ~1.5e-3)
//     + bit-trick reciprocal w/ 2 Newton steps => ZERO transcendental ops.
//     Inner loop vectorized over direction pairs (L,R)/(U,D) as float2 so
//     clang emits v_pk_fma_f32 (packed fp32, 2 ops/instr).

#define GW   512
#define GN   (GW * GW)
#define HID  64
#define NUC  0.01f

typedef float        v2f __attribute__((ext_vector_type(2)));
typedef unsigned int v2u __attribute__((ext_vector_type(2)));

__device__ __forceinline__ v2f bc(float x) { v2f r; r.x = x; r.y = x; return r; }

// tanh(x) ~= t(945+105t^2+t^4)/(945+420t^2+15t^4), t=clamp(x,+-3.8)
// Division via magic-constant reciprocal + 2 Newton iterations (all VALU).
__device__ __forceinline__ v2f tanh2(v2f x) {
    v2f t;
    t.x = __builtin_amdgcn_fmed3f(x.x, -3.8f, 3.8f);
    t.y = __builtin_amdgcn_fmed3f(x.y, -3.8f, 3.8f);
    v2f s   = t * t;
    v2f num = t * __builtin_elementwise_fma(s, s + bc(105.f), bc(945.f));
    v2f den = __builtin_elementwise_fma(
                  s, __builtin_elementwise_fma(s, bc(15.f), bc(420.f)), bc(945.f));
    v2u qi = __builtin_bit_cast(v2u, den);
    v2u ri; ri.x = 0x7EF311C3u - qi.x; ri.y = 0x7EF311C3u - qi.y;
    v2f r  = __builtin_bit_cast(v2f, ri);
    r = r * __builtin_elementwise_fma(-den, r, bc(2.f));   // Newton 1
    r = r * __builtin_elementwise_fma(-den, r, bc(2.f));   // Newton 2
    return num * r;
}

struct alignas(16) LW {
    float a0, a1, a2, a3;    // W1 rows 0..3 for this hidden unit
    v2f   kLR, kUD;          // b1 + ea.W1[4:6] folded per incoming direction
    float c0, c1, p0, p1;    // W2 row
};

__device__ __forceinline__ void fill_lds(LW* lw, float* sb2,
                                         const float* __restrict__ W1,
                                         const float* __restrict__ b1,
                                         const float* __restrict__ W2,
                                         const float* __restrict__ b2) {
    const int t = threadIdx.x;
    if (t < HID) {
        const float H = 1.0f / 511.0f;
        float a4 = W1[4 * HID + t], a5 = W1[5 * HID + t];
        float b  = b1[t];
        LW w;
        w.a0 = W1[0 * HID + t]; w.a1 = W1[1 * HID + t];
        w.a2 = W1[2 * HID + t]; w.a3 = W1[3 * HID + t];
        w.kLR.x = b - H * a4;  w.kLR.y = b + H * a4;   // from left / from right
        w.kUD.x = b - H * a5;  w.kUD.y = b + H * a5;   // from up / from down
        w.c0 = W2[2 * t + 0];  w.c1 = W2[2 * t + 1];
        w.p0 = 0.f; w.p1 = 0.f;
        lw[t] = w;
    }
    if (t < 2) sb2[t] = b2[t];
}

// Kernel 1: grad_u, grad_v, grad_p. SoA out: g[0]=gu0 g[1]=gu1 ... g[5]=gp1
__global__ void __launch_bounds__(256) grad3_kernel(
    const float* __restrict__ fields, const float* __restrict__ degrees,
    const float* __restrict__ W1, const float* __restrict__ b1,
    const float* __restrict__ W2, const float* __restrict__ b2,
    float* __restrict__ g)
{
    __shared__ LW lw[HID];
    __shared__ float sb2[2];
    fill_lds(lw, sb2, W1, b1, W2, b2);
    __syncthreads();

    const int idx = blockIdx.x * 256 + threadIdx.x;
    const int row = idx >> 9, col = idx & (GW - 1);
    const bool vE0 = col > 0, vE1 = col < GW - 1, vE2 = row > 0, vE3 = row < GW - 1;
    int nb[4];
    nb[0] = vE0 ? idx - 1  : idx;
    nb[1] = vE1 ? idx + 1  : idx;
    nb[2] = vE2 ? idx - GW : idx;
    nb[3] = vE3 ? idx + GW : idx;

    float s0[3];
    #pragma unroll
    for (int f = 0; f < 3; ++f) s0[f] = fields[3 * idx + f];
    v2f sN2[2][3];                       // [pair LR/UD][field]
    #pragma unroll
    for (int f = 0; f < 3; ++f) {
        sN2[0][f].x = fields[3 * nb[0] + f]; sN2[0][f].y = fields[3 * nb[1] + f];
        sN2[1][f].x = fields[3 * nb[2] + f]; sN2[1][f].y = fields[3 * nb[3] + f];
    }
    v2f dnbLR, dnbUD;
    dnbLR.x = degrees[nb[0]]; dnbLR.y = degrees[nb[1]];
    dnbUD.x = degrees[nb[2]]; dnbUD.y = degrees[nb[3]];
    const float dN = degrees[idx];

    v2f acc[2][3][2];
    #pragma unroll
    for (int dp = 0; dp < 2; ++dp)
        #pragma unroll
        for (int f = 0; f < 3; ++f) { acc[dp][f][0] = bc(0.f); acc[dp][f][1] = bc(0.f); }

    #pragma unroll 2
    for (int j = 0; j < HID; ++j) {
        LW w = lw[j];
        const float dn1 = dN * w.a1;
        v2f hb[2];
        hb[0] = __builtin_elementwise_fma(dnbLR, bc(w.a3), w.kLR + bc(dn1));
        hb[1] = __builtin_elementwise_fma(dnbUD, bc(w.a3), w.kUD + bc(dn1));
        #pragma unroll
        for (int f = 0; f < 3; ++f) {
            const float pf = s0[f] * w.a0;
            #pragma unroll
            for (int dp = 0; dp < 2; ++dp) {
                v2f h  = __builtin_elementwise_fma(sN2[dp][f], bc(w.a2), hb[dp] + bc(pf));
                v2f th = tanh2(h);
                acc[dp][f][0] = __builtin_elementwise_fma(th, bc(w.c0), acc[dp][f][0]);
                acc[dp][f][1] = __builtin_elementwise_fma(th, bc(w.c1), acc[dp][f][1]);
            }
        }
    }

    const float rd = __builtin_amdgcn_rcpf(dN);
    #pragma unroll
    for (int f = 0; f < 3; ++f) {
        #pragma unroll
        for (int c = 0; c < 2; ++c) {
            float s = 0.f;
            s += vE0 ? acc[0][f][c].x : 0.f;
            s += vE1 ? acc[0][f][c].y : 0.f;
            s += vE2 ? acc[1][f][c].x : 0.f;
            s += vE3 ? acc[1][f][c].y : 0.f;
            g[(2 * f + c) * GN + idx] = __builtin_fmaf(s, rd, sb2[c]);
        }
    }
}

// Kernel 2: second-order g on gu0,gu1,gv0,gv1 (needed comps 0,1,0,1) + combine.
__global__ void __launch_bounds__(256) final_kernel(
    const float* __restrict__ fields, const float* __restrict__ degrees,
    const float* __restrict__ W1, const float* __restrict__ b1,
    const float* __restrict__ W2, const float* __restrict__ b2,
    const float* __restrict__ g, float* __restrict__ out)
{
    __shared__ LW lw[HID];
    __shared__ float sb2[2];
    fill_lds(lw, sb2, W1, b1, W2, b2);
    __syncthreads();

    const int idx = blockIdx.x * 256 + threadIdx.x;
    const int row = idx >> 9, col = idx & (GW - 1);
    const bool vE0 = col > 0, vE1 = col < GW - 1, vE2 = row > 0, vE3 = row < GW - 1;
    int nb[4];
    nb[0] = vE0 ? idx - 1  : idx;
    nb[1] = vE1 ? idx + 1  : idx;
    nb[2] = vE2 ? idx - GW : idx;
    nb[3] = vE3 ? idx + GW : idx;

    float s0[4];
    #pragma unroll
    for (int f = 0; f < 4; ++f) s0[f] = g[f * GN + idx];
    v2f sN2[2][4];
    #pragma unroll
    for (int f = 0; f < 4; ++f) {
        sN2[0][f].x = g[f * GN + nb[0]]; sN2[0][f].y = g[f * GN + nb[1]];
        sN2[1][f].x = g[f * GN + nb[2]]; sN2[1][f].y = g[f * GN + nb[3]];
    }
    v2f dnbLR, dnbUD;
    dnbLR.x = degrees[nb[0]]; dnbLR.y = degrees[nb[1]];
    dnbUD.x = degrees[nb[2]]; dnbUD.y = degrees[nb[3]];
    const float dN = degrees[idx];

    v2f acc[2][4];
    #pragma unroll
    for (int dp = 0; dp < 2; ++dp)
        #pragma unroll
        for (int f = 0; f < 4; ++f) acc[dp][f] = bc(0.f);

    #pragma unroll 2
    for (int j = 0; j < HID; ++j) {
        LW w = lw[j];
        const float dn1 = dN * w.a1;
        v2f hb[2];
        hb[0] = __builtin_elementwise_fma(dnbLR, bc(w.a3), w.kLR + bc(dn1));
        hb[1] = __builtin_elementwise_fma(dnbUD, bc(w.a3), w.kUD + bc(dn1));
        #pragma unroll
        for (int f = 0; f < 4; ++f) {
            const float pf = s0[f] * w.a0;
            const float cc = (f & 1) ? w.c1 : w.c0;
            #pragma unroll
            for (int dp = 0; dp < 2; ++dp) {
                v2f h  = __builtin_elementwise_fma(sN2[dp][f], bc(w.a2), hb[dp] + bc(pf));
                v2f th = tanh2(h);
                acc[dp][f] = __builtin_elementwise_fma(th, bc(cc), acc[dp][f]);
            }
        }
    }

    const float rd = __builtin_amdgcn_rcpf(dN);
    float r[4];
    #pragma unroll
    for (int f = 0; f < 4; ++f) {
        float s = 0.f;
        s += vE0 ? acc[0][f].x : 0.f;
        s += vE1 ? acc[0][f].y : 0.f;
        s += vE2 ? acc[1][f].x : 0.f;
        s += vE3 ? acc[1][f].y : 0.f;
        r[f] = __builtin_fmaf(s, rd, sb2[f & 1]);
    }
    const float lap_u = r[0] + r[1];
    const float lap_v = r[2] + r[3];

    const float u = fields[3 * idx + 0], v = fields[3 * idx + 1];
    const float gu0 = s0[0], gu1 = s0[1], gv0 = s0[2], gv1 = s0[3];
    const float gp0 = g[4 * GN + idx], gp1 = g[5 * GN + idx];

    out[3 * idx + 0] = gu0 + gv1;
    out[3 * idx + 1] = u * gu0 + v * gu1 + gp0 - NUC * lap_u;
    out[3 * idx + 2] = u * gv0 + v * gv1 + gp1 - NUC * lap_v;
}

extern "C" void kernel_launch(void* const* d_in, const int* in_sizes, int n_in,
                              void* d_out, int out_size, void* d_ws, size_t ws_size,
                              hipStream_t stream) {
    const float* fields  = (const float*)d_in[0];
    const float* degrees = (const float*)d_in[1];
    const float* W1 = (const float*)d_in[3];
    const float* b1 = (const float*)d_in[4];
    const float* W2 = (const float*)d_in[5];
    const float* b2 = (const float*)d_in[6];
    float* g   = (float*)d_ws;           // 6 * GN floats = 6.3 MB scratch
    float* out = (float*)d_out;

    grad3_kernel<<<GN / 256, 256, 0, stream>>>(fields, degrees, W1, b1, W2, b2, g);
    final_kernel<<<GN / 256, 256, 0, stream>>>(fields, degrees, W1, b1, W2, b2, g, out);
}

// Round 4
// 203.268 us; speedup vs baseline: 1.0598x; 1.0598x over previous
//
#include <hip/hip_runtime.h>

// Grid: 512x512 nodes, idx = row*512 + col. h = 1/511.
// m_in = [s_dst, deg_dst, s_src, deg_src, ea_x, ea_y] @ W1 -> tanh -> @ W2
// g(s)[n] = (1/deg_n) * sum_incoming(msg) + b2
//
// R3 (= R2 retry with clang-native f16 vectors): entire inner loop in packed
// f16 (v_pk_*_f16 via _Float16 ext_vector_type(2) operators — ROCm's __half2
// API has broken __hmin2/__hmax2 overloads). 2 units (L,R)/(U,D) per instr.
// tanh = Pade[5/4]; reciprocal via 32-bit magic subtract (den in [945,10114]
// -> no cross-half borrow) + 2 packed Newton steps. Zero transcendentals.
// Two j-phase accumulators limit f16 accumulation error.

#define GW   512
#define GN   (GW * GW)
#define HID  64
#define NUC  0.01f

typedef _Float16 h2 __attribute__((ext_vector_type(2)));

__device__ __forceinline__ h2 h2c(float x) {
    h2 r; r.x = (_Float16)x; r.y = (_Float16)x; return r;
}
__device__ __forceinline__ h2 h2p(float a, float b) {
    h2 r; r.x = (_Float16)a; r.y = (_Float16)b; return r;
}

// tanh(t) ~= t(945+105t^2+t^4)/(945+420t^2+15t^4), t=clamp(x,+-3.8), all pk f16.
__device__ __forceinline__ h2 tanh2h(h2 x) {
    h2 t = __builtin_elementwise_min(h2c(3.8f),
             __builtin_elementwise_max(h2c(-3.8f), x));
    h2 s   = t * t;
    h2 num = t * __builtin_elementwise_fma(s, s + h2c(105.f), h2c(945.f));
    h2 den = __builtin_elementwise_fma(
                 s, __builtin_elementwise_fma(s, h2c(15.f), h2c(420.f)), h2c(945.f));
    // magic reciprocal seed: both halves of den in [945,10114] => bits
    // <= 0x70F1 < 0x7798, so one 32-bit subtract never borrows across halves.
    unsigned int ri = 0x77987798u - __builtin_bit_cast(unsigned int, den);
    h2 r = __builtin_bit_cast(h2, ri);
    r = r * __builtin_elementwise_fma(-den, r, h2c(2.f));   // Newton 1
    r = r * __builtin_elementwise_fma(-den, r, h2c(2.f));   // Newton 2
    return num * r;
}

struct alignas(16) LWH {           // 32 B per hidden unit, broadcast pairs
    h2 a0, a1, a2, a3;             // W1 rows 0..3 (duplicated into both halves)
    h2 kLR, kUD;                   // b1 + ea.W1[4:6] folded per incoming dir
    h2 c0, c1;                     // W2 row (duplicated)
};

__device__ __forceinline__ void fill_lds(LWH* lw, float* sb2,
                                         const float* __restrict__ W1,
                                         const float* __restrict__ b1,
                                         const float* __restrict__ W2,
                                         const float* __restrict__ b2) {
    const int t = threadIdx.x;
    if (t < HID) {
        const float H = 1.0f / 511.0f;
        float a4 = W1[4 * HID + t], a5 = W1[5 * HID + t];
        float b  = b1[t];
        LWH w;
        w.a0 = h2c(W1[0 * HID + t]); w.a1 = h2c(W1[1 * HID + t]);
        w.a2 = h2c(W1[2 * HID + t]); w.a3 = h2c(W1[3 * HID + t]);
        w.kLR = h2p(b - H * a4, b + H * a4);  // from left / from right
        w.kUD = h2p(b - H * a5, b + H * a5);  // from up / from down
        w.c0 = h2c(W2[2 * t + 0]);  w.c1 = h2c(W2[2 * t + 1]);
        lw[t] = w;
    }
    if (t < 2) sb2[t] = b2[t];
}

// Kernel 1: grad_u, grad_v, grad_p. SoA out: g[0]=gu0 g[1]=gu1 ... g[5]=gp1
__global__ void __launch_bounds__(256) grad3_kernel(
    const float* __restrict__ fields, const float* __restrict__ degrees,
    const float* __restrict__ W1, const float* __restrict__ b1,
    const float* __restrict__ W2, const float* __restrict__ b2,
    float* __restrict__ g)
{
    __shared__ LWH lw[HID];
    __shared__ float sb2[2];
    fill_lds(lw, sb2, W1, b1, W2, b2);
    __syncthreads();

    const int idx = blockIdx.x * 256 + threadIdx.x;
    const int row = idx >> 9, col = idx & (GW - 1);
    const bool vE0 = col > 0, vE1 = col < GW - 1, vE2 = row > 0, vE3 = row < GW - 1;
    int nb[4];
    nb[0] = vE0 ? idx - 1  : idx;
    nb[1] = vE1 ? idx + 1  : idx;
    nb[2] = vE2 ? idx - GW : idx;
    nb[3] = vE3 ? idx + GW : idx;

    h2 s0h[3];
    #pragma unroll
    for (int f = 0; f < 3; ++f) s0h[f] = h2c(fields[3 * idx + f]);
    h2 sN2[2][3];                       // [pair LR/UD][field]
    #pragma unroll
    for (int f = 0; f < 3; ++f) {
        sN2[0][f] = h2p(fields[3 * nb[0] + f], fields[3 * nb[1] + f]);
        sN2[1][f] = h2p(fields[3 * nb[2] + f], fields[3 * nb[3] + f]);
    }
    h2 dnbLR = h2p(degrees[nb[0]], degrees[nb[1]]);
    h2 dnbUD = h2p(degrees[nb[2]], degrees[nb[3]]);
    const float dN = degrees[idx];
    const h2 dNh = h2c(dN);

    h2 acc[2][2][3][2];                 // [phase][pair][field][W2 comp]
    #pragma unroll
    for (int ph = 0; ph < 2; ++ph)
        #pragma unroll
        for (int dp = 0; dp < 2; ++dp)
            #pragma unroll
            for (int f = 0; f < 3; ++f) {
                acc[ph][dp][f][0] = h2c(0.f); acc[ph][dp][f][1] = h2c(0.f);
            }

    #pragma unroll 2
    for (int j = 0; j < HID; ++j) {
        LWH w = lw[j];
        const int ph = j & 1;
        h2 dn1 = dNh * w.a1;
        h2 hb[2];
        hb[0] = __builtin_elementwise_fma(dnbLR, w.a3, w.kLR + dn1);
        hb[1] = __builtin_elementwise_fma(dnbUD, w.a3, w.kUD + dn1);
        #pragma unroll
        for (int f = 0; f < 3; ++f) {
            h2 pf = s0h[f] * w.a0;
            #pragma unroll
            for (int dp = 0; dp < 2; ++dp) {
                h2 hh = __builtin_elementwise_fma(sN2[dp][f], w.a2, hb[dp] + pf);
                h2 th = tanh2h(hh);
                acc[ph][dp][f][0] = __builtin_elementwise_fma(th, w.c0, acc[ph][dp][f][0]);
                acc[ph][dp][f][1] = __builtin_elementwise_fma(th, w.c1, acc[ph][dp][f][1]);
            }
        }
    }

    const float rd = __builtin_amdgcn_rcpf(dN);
    #pragma unroll
    for (int f = 0; f < 3; ++f) {
        #pragma unroll
        for (int c = 0; c < 2; ++c) {
            float s = 0.f;
            #pragma unroll
            for (int ph = 0; ph < 2; ++ph) {
                s += vE0 ? (float)acc[ph][0][f][c].x : 0.f;
                s += vE1 ? (float)acc[ph][0][f][c].y : 0.f;
                s += vE2 ? (float)acc[ph][1][f][c].x : 0.f;
                s += vE3 ? (float)acc[ph][1][f][c].y : 0.f;
            }
            g[(2 * f + c) * GN + idx] = __builtin_fmaf(s, rd, sb2[c]);
        }
    }
}

// Kernel 2: second-order g on gu0,gu1,gv0,gv1 (needed comps 0,1,0,1) + combine.
__global__ void __launch_bounds__(256) final_kernel(
    const float* __restrict__ fields, const float* __restrict__ degrees,
    const float* __restrict__ W1, const float* __restrict__ b1,
    const float* __restrict__ W2, const float* __restrict__ b2,
    const float* __restrict__ g, float* __restrict__ out)
{
    __shared__ LWH lw[HID];
    __shared__ float sb2[2];
    fill_lds(lw, sb2, W1, b1, W2, b2);
    __syncthreads();

    const int idx = blockIdx.x * 256 + threadIdx.x;
    const int row = idx >> 9, col = idx & (GW - 1);
    const bool vE0 = col > 0, vE1 = col < GW - 1, vE2 = row > 0, vE3 = row < GW - 1;
    int nb[4];
    nb[0] = vE0 ? idx - 1  : idx;
    nb[1] = vE1 ? idx + 1  : idx;
    nb[2] = vE2 ? idx - GW : idx;
    nb[3] = vE3 ? idx + GW : idx;

    float s0[4];
    #pragma unroll
    for (int f = 0; f < 4; ++f) s0[f] = g[f * GN + idx];
    h2 s0h[4];
    #pragma unroll
    for (int f = 0; f < 4; ++f) s0h[f] = h2c(s0[f]);
    h2 sN2[2][4];
    #pragma unroll
    for (int f = 0; f < 4; ++f) {
        sN2[0][f] = h2p(g[f * GN + nb[0]], g[f * GN + nb[1]]);
        sN2[1][f] = h2p(g[f * GN + nb[2]], g[f * GN + nb[3]]);
    }
    h2 dnbLR = h2p(degrees[nb[0]], degrees[nb[1]]);
    h2 dnbUD = h2p(degrees[nb[2]], degrees[nb[3]]);
    const float dN = degrees[idx];
    const h2 dNh = h2c(dN);

    h2 acc[2][2][4];                    // [phase][pair][field]
    #pragma unroll
    for (int ph = 0; ph < 2; ++ph)
        #pragma unroll
        for (int dp = 0; dp < 2; ++dp)
            #pragma unroll
            for (int f = 0; f < 4; ++f) acc[ph][dp][f] = h2c(0.f);

    #pragma unroll 2
    for (int j = 0; j < HID; ++j) {
        LWH w = lw[j];
        const int ph = j & 1;
        h2 dn1 = dNh * w.a1;
        h2 hb[2];
        hb[0] = __builtin_elementwise_fma(dnbLR, w.a3, w.kLR + dn1);
        hb[1] = __builtin_elementwise_fma(dnbUD, w.a3, w.kUD + dn1);
        #pragma unroll
        for (int f = 0; f < 4; ++f) {
            h2 pf = s0h[f] * w.a0;
            h2 cc = (f & 1) ? w.c1 : w.c0;   // needed comp: 0,1,0,1
            #pragma unroll
            for (int dp = 0; dp < 2; ++dp) {
                h2 hh = __builtin_elementwise_fma(sN2[dp][f], w.a2, hb[dp] + pf);
                h2 th = tanh2h(hh);
                acc[ph][dp][f] = __builtin_elementwise_fma(th, cc, acc[ph][dp][f]);
            }
        }
    }

    const float rd = __builtin_amdgcn_rcpf(dN);
    float r[4];
    #pragma unroll
    for (int f = 0; f < 4; ++f) {
        float s = 0.f;
        #pragma unroll
        for (int ph = 0; ph < 2; ++ph) {
            s += vE0 ? (float)acc[ph][0][f].x : 0.f;
            s += vE1 ? (float)acc[ph][0][f].y : 0.f;
            s += vE2 ? (float)acc[ph][1][f].x : 0.f;
            s += vE3 ? (float)acc[ph][1][f].y : 0.f;
        }
        r[f] = __builtin_fmaf(s, rd, sb2[f & 1]);
    }
    const float lap_u = r[0] + r[1];
    const float lap_v = r[2] + r[3];

    const float u = fields[3 * idx + 0], v = fields[3 * idx + 1];
    const float gu0 = s0[0], gu1 = s0[1], gv0 = s0[2], gv1 = s0[3];
    const float gp0 = g[4 * GN + idx], gp1 = g[5 * GN + idx];

    out[3 * idx + 0] = gu0 + gv1;
    out[3 * idx + 1] = u * gu0 + v * gu1 + gp0 - NUC * lap_u;
    out[3 * idx + 2] = u * gv0 + v * gv1 + gp1 - NUC * lap_v;
}

extern "C" void kernel_launch(void* const* d_in, const int* in_sizes, int n_in,
                              void* d_out, int out_size, void* d_ws, size_t ws_size,
                              hipStream_t stream) {
    const float* fields  = (const float*)d_in[0];
    const float* degrees = (const float*)d_in[1];
    const float* W1 = (const float*)d_in[3];
    const float* b1 = (const float*)d_in[4];
    const float* W2 = (const float*)d_in[5];
    const float* b2 = (const float*)d_in[6];
    float* g   = (float*)d_ws;           // 6 * GN floats = 6.3 MB scratch
    float* out = (float*)d_out;

    grad3_kernel<<<GN / 256, 256, 0, stream>>>(fields, degrees, W1, b1, W2, b2, g);
    final_kernel<<<GN / 256, 256, 0, stream>>>(fields, degrees, W1, b1, W2, b2, g, out);
}

// Round 5
// 197.909 us; speedup vs baseline: 1.0885x; 1.0271x over previous
//
#include <hip/hip_runtime.h>

// Grid: 512x512 nodes, idx = row*512 + col. h = 1/511.
// m_in = [s_dst, deg_dst, s_src, deg_src, ea_x, ea_y] @ W1 -> tanh -> @ W2
// g(s)[n] = (1/deg_n) * sum_incoming(msg) + b2
//
// R4: R3 algorithm, but packed f16 is FORCED via inline asm (v_pk_*_f16) —
// evidence from R1/R3 shows clang scalarizes ext_vector f16/f32 math on
// gfx950 (measured issue time matched the scalarized count exactly).
// tanh = Pade[5/4] in pk f16; reciprocal = 16-bit magic subtract (den in
// [945,10114] -> no cross-half borrow in a 32-bit sub) + ONE packed Newton
// step. Zero transcendentals. Two j-phase accumulators limit f16 error.

#define GW   512
#define GN   (GW * GW)
#define HID  64
#define NUC  0.01f

typedef _Float16 h2 __attribute__((ext_vector_type(2)));

__device__ __forceinline__ float h2f(h2 x) { return __builtin_bit_cast(float, x); }
__device__ __forceinline__ h2 f2h(float x) { return __builtin_bit_cast(h2, x); }

// Inline-asm packed f16 helpers: operands proxied as 32-bit floats so clang
// assigns a plain single VGPR to each. Guaranteed v_pk_* issue.
__device__ __forceinline__ h2 pk_fma(h2 a, h2 b, h2 c) {
    float d, fa = h2f(a), fb = h2f(b), fc = h2f(c);
    asm("v_pk_fma_f16 %0, %1, %2, %3" : "=v"(d) : "v"(fa), "v"(fb), "v"(fc));
    return f2h(d);
}
__device__ __forceinline__ h2 pk_mul(h2 a, h2 b) {
    float d, fa = h2f(a), fb = h2f(b);
    asm("v_pk_mul_f16 %0, %1, %2" : "=v"(d) : "v"(fa), "v"(fb));
    return f2h(d);
}
__device__ __forceinline__ h2 pk_add(h2 a, h2 b) {
    float d, fa = h2f(a), fb = h2f(b);
    asm("v_pk_add_f16 %0, %1, %2" : "=v"(d) : "v"(fa), "v"(fb));
    return f2h(d);
}
__device__ __forceinline__ h2 pk_min(h2 a, h2 b) {
    float d, fa = h2f(a), fb = h2f(b);
    asm("v_pk_min_f16 %0, %1, %2" : "=v"(d) : "v"(fa), "v"(fb));
    return f2h(d);
}
__device__ __forceinline__ h2 pk_max(h2 a, h2 b) {
    float d, fa = h2f(a), fb = h2f(b);
    asm("v_pk_max_f16 %0, %1, %2" : "=v"(d) : "v"(fa), "v"(fb));
    return f2h(d);
}

__device__ __forceinline__ h2 h2c(float x) {
    h2 r; r.x = (_Float16)x; r.y = (_Float16)x; return r;
}
__device__ __forceinline__ h2 h2p(float a, float b) {
    h2 r; r.x = (_Float16)a; r.y = (_Float16)b; return r;
}

struct TanhC { h2 c38, cm38, c105, c945, c15, c420, c2; };
__device__ __forceinline__ TanhC make_tc() {
    TanhC t;
    t.c38 = h2c(3.8f); t.cm38 = h2c(-3.8f); t.c105 = h2c(105.f);
    t.c945 = h2c(945.f); t.c15 = h2c(15.f); t.c420 = h2c(420.f); t.c2 = h2c(2.f);
    return t;
}

// tanh(t) ~= t(945+105s+s^2)/(945+420s+15s^2), s=t^2, t=clamp(x,+-3.8).
// 13 pk instrs, zero transcendentals.
__device__ __forceinline__ h2 tanh_pk(h2 x, const TanhC& tc) {
    h2 t   = pk_min(tc.c38, pk_max(tc.cm38, x));
    h2 s   = pk_mul(t, t);
    h2 num = pk_mul(t, pk_fma(s, pk_add(s, tc.c105), tc.c945));
    h2 den = pk_fma(s, pk_fma(s, tc.c15, tc.c420), tc.c945);
    unsigned int db = __builtin_bit_cast(unsigned int, den);
    h2 r   = __builtin_bit_cast(h2, 0x77987798u - db);         // magic seed
    h2 nd  = __builtin_bit_cast(h2, db ^ 0x80008000u);         // -den
    r = pk_mul(r, pk_fma(nd, r, tc.c2));                       // Newton 1
    return pk_mul(num, r);
}

struct alignas(16) LWH {           // 32 B per hidden unit, broadcast pairs
    h2 a0, a1, a2, a3;             // W1 rows 0..3 (duplicated into both halves)
    h2 kLR, kUD;                   // b1 + ea.W1[4:6] folded per incoming dir
    h2 c0, c1;                     // W2 row (duplicated)
};

__device__ __forceinline__ void fill_lds(LWH* lw, float* sb2,
                                         const float* __restrict__ W1,
                                         const float* __restrict__ b1,
                                         const float* __restrict__ W2,
                                         const float* __restrict__ b2) {
    const int t = threadIdx.x;
    if (t < HID) {
        const float H = 1.0f / 511.0f;
        float a4 = W1[4 * HID + t], a5 = W1[5 * HID + t];
        float b  = b1[t];
        LWH w;
        w.a0 = h2c(W1[0 * HID + t]); w.a1 = h2c(W1[1 * HID + t]);
        w.a2 = h2c(W1[2 * HID + t]); w.a3 = h2c(W1[3 * HID + t]);
        w.kLR = h2p(b - H * a4, b + H * a4);  // from left / from right
        w.kUD = h2p(b - H * a5, b + H * a5);  // from up / from down
        w.c0 = h2c(W2[2 * t + 0]);  w.c1 = h2c(W2[2 * t + 1]);
        lw[t] = w;
    }
    if (t < 2) sb2[t] = b2[t];
}

// Kernel 1: grad_u, grad_v, grad_p. SoA out: g[0]=gu0 g[1]=gu1 ... g[5]=gp1
__global__ void __launch_bounds__(256) grad3_kernel(
    const float* __restrict__ fields, const float* __restrict__ degrees,
    const float* __restrict__ W1, const float* __restrict__ b1,
    const float* __restrict__ W2, const float* __restrict__ b2,
    float* __restrict__ g)
{
    __shared__ LWH lw[HID];
    __shared__ float sb2[2];
    fill_lds(lw, sb2, W1, b1, W2, b2);
    __syncthreads();

    const int idx = blockIdx.x * 256 + threadIdx.x;
    const int row = idx >> 9, col = idx & (GW - 1);
    const bool vE0 = col > 0, vE1 = col < GW - 1, vE2 = row > 0, vE3 = row < GW - 1;
    int nb[4];
    nb[0] = vE0 ? idx - 1  : idx;
    nb[1] = vE1 ? idx + 1  : idx;
    nb[2] = vE2 ? idx - GW : idx;
    nb[3] = vE3 ? idx + GW : idx;

    const TanhC tc = make_tc();

    h2 s0h[3];
    #pragma unroll
    for (int f = 0; f < 3; ++f) s0h[f] = h2c(fields[3 * idx + f]);
    h2 sN2[2][3];                       // [pair LR/UD][field]
    #pragma unroll
    for (int f = 0; f < 3; ++f) {
        sN2[0][f] = h2p(fields[3 * nb[0] + f], fields[3 * nb[1] + f]);
        sN2[1][f] = h2p(fields[3 * nb[2] + f], fields[3 * nb[3] + f]);
    }
    h2 dnbLR = h2p(degrees[nb[0]], degrees[nb[1]]);
    h2 dnbUD = h2p(degrees[nb[2]], degrees[nb[3]]);
    const float dN = degrees[idx];
    const h2 dNh = h2c(dN);

    h2 acc[2][2][3][2];                 // [phase][pair][field][W2 comp]
    #pragma unroll
    for (int ph = 0; ph < 2; ++ph)
        #pragma unroll
        for (int dp = 0; dp < 2; ++dp)
            #pragma unroll
            for (int f = 0; f < 3; ++f) {
                acc[ph][dp][f][0] = h2c(0.f); acc[ph][dp][f][1] = h2c(0.f);
            }

    #pragma unroll 2
    for (int j = 0; j < HID; ++j) {
        LWH w = lw[j];
        const int ph = j & 1;
        h2 dn1 = pk_mul(dNh, w.a1);
        h2 hb[2];
        hb[0] = pk_fma(dnbLR, w.a3, pk_add(w.kLR, dn1));
        hb[1] = pk_fma(dnbUD, w.a3, pk_add(w.kUD, dn1));
        #pragma unroll
        for (int f = 0; f < 3; ++f) {
            #pragma unroll
            for (int dp = 0; dp < 2; ++dp) {
                h2 hh = pk_fma(sN2[dp][f], w.a2, pk_fma(s0h[f], w.a0, hb[dp]));
                h2 th = tanh_pk(hh, tc);
                acc[ph][dp][f][0] = pk_fma(th, w.c0, acc[ph][dp][f][0]);
                acc[ph][dp][f][1] = pk_fma(th, w.c1, acc[ph][dp][f][1]);
            }
        }
    }

    const float rd = __builtin_amdgcn_rcpf(dN);
    #pragma unroll
    for (int f = 0; f < 3; ++f) {
        #pragma unroll
        for (int c = 0; c < 2; ++c) {
            float s = 0.f;
            #pragma unroll
            for (int ph = 0; ph < 2; ++ph) {
                s += vE0 ? (float)acc[ph][0][f][c].x : 0.f;
                s += vE1 ? (float)acc[ph][0][f][c].y : 0.f;
                s += vE2 ? (float)acc[ph][1][f][c].x : 0.f;
                s += vE3 ? (float)acc[ph][1][f][c].y : 0.f;
            }
            g[(2 * f + c) * GN + idx] = __builtin_fmaf(s, rd, sb2[c]);
        }
    }
}

// Kernel 2: second-order g on gu0,gu1,gv0,gv1 (needed comps 0,1,0,1) + combine.
__global__ void __launch_bounds__(256) final_kernel(
    const float* __restrict__ fields, const float* __restrict__ degrees,
    const float* __restrict__ W1, const float* __restrict__ b1,
    const float* __restrict__ W2, const float* __restrict__ b2,
    const float* __restrict__ g, float* __restrict__ out)
{
    __shared__ LWH lw[HID];
    __shared__ float sb2[2];
    fill_lds(lw, sb2, W1, b1, W2, b2);
    __syncthreads();

    const int idx = blockIdx.x * 256 + threadIdx.x;
    const int row = idx >> 9, col = idx & (GW - 1);
    const bool vE0 = col > 0, vE1 = col < GW - 1, vE2 = row > 0, vE3 = row < GW - 1;
    int nb[4];
    nb[0] = vE0 ? idx - 1  : idx;
    nb[1] = vE1 ? idx + 1  : idx;
    nb[2] = vE2 ? idx - GW : idx;
    nb[3] = vE3 ? idx + GW : idx;

    const TanhC tc = make_tc();

    float s0[4];
    #pragma unroll
    for (int f = 0; f < 4; ++f) s0[f] = g[f * GN + idx];
    h2 s0h[4];
    #pragma unroll
    for (int f = 0; f < 4; ++f) s0h[f] = h2c(s0[f]);
    h2 sN2[2][4];
    #pragma unroll
    for (int f = 0; f < 4; ++f) {
        sN2[0][f] = h2p(g[f * GN + nb[0]], g[f * GN + nb[1]]);
        sN2[1][f] = h2p(g[f * GN + nb[2]], g[f * GN + nb[3]]);
    }
    h2 dnbLR = h2p(degrees[nb[0]], degrees[nb[1]]);
    h2 dnbUD = h2p(degrees[nb[2]], degrees[nb[3]]);
    const float dN = degrees[idx];
    const h2 dNh = h2c(dN);

    h2 acc[2][2][4];                    // [phase][pair][field]
    #pragma unroll
    for (int ph = 0; ph < 2; ++ph)
        #pragma unroll
        for (int dp = 0; dp < 2; ++dp)
            #pragma unroll
            for (int f = 0; f < 4; ++f) acc[ph][dp][f] = h2c(0.f);

    #pragma unroll 2
    for (int j = 0; j < HID; ++j) {
        LWH w = lw[j];
        const int ph = j & 1;
        h2 dn1 = pk_mul(dNh, w.a1);
        h2 hb[2];
        hb[0] = pk_fma(dnbLR, w.a3, pk_add(w.kLR, dn1));
        hb[1] = pk_fma(dnbUD, w.a3, pk_add(w.kUD, dn1));
        #pragma unroll
        for (int f = 0; f < 4; ++f) {
            h2 cc = (f & 1) ? w.c1 : w.c0;   // needed comp: 0,1,0,1
            #pragma unroll
            for (int dp = 0; dp < 2; ++dp) {
                h2 hh = pk_fma(sN2[dp][f], w.a2, pk_fma(s0h[f], w.a0, hb[dp]));
                h2 th = tanh_pk(hh, tc);
                acc[ph][dp][f] = pk_fma(th, cc, acc[ph][dp][f]);
            }
        }
    }

    const float rd = __builtin_amdgcn_rcpf(dN);
    float r[4];
    #pragma unroll
    for (int f = 0; f < 4; ++f) {
        float s = 0.f;
        #pragma unroll
        for (int ph = 0; ph < 2; ++ph) {
            s += vE0 ? (float)acc[ph][0][f].x : 0.f;
            s += vE1 ? (float)acc[ph][0][f].y : 0.f;
            s += vE2 ? (float)acc[ph][1][f].x : 0.f;
            s += vE3 ? (float)acc[ph][1][f].y : 0.f;
        }
        r[f] = __builtin_fmaf(s, rd, sb2[f & 1]);
    }
    const float lap_u = r[0] + r[1];
    const float lap_v = r[2] + r[3];

    const float u = fields[3 * idx + 0], v = fields[3 * idx + 1];
    const float gu0 = s0[0], gu1 = s0[1], gv0 = s0[2], gv1 = s0[3];
    const float gp0 = g[4 * GN + idx], gp1 = g[5 * GN + idx];

    out[3 * idx + 0] = gu0 + gv1;
    out[3 * idx + 1] = u * gu0 + v * gu1 + gp0 - NUC * lap_u;
    out[3 * idx + 2] = u * gv0 + v * gv1 + gp1 - NUC * lap_v;
}

extern "C" void kernel_launch(void* const* d_in, const int* in_sizes, int n_in,
                              void* d_out, int out_size, void* d_ws, size_t ws_size,
                              hipStream_t stream) {
    const float* fields  = (const float*)d_in[0];
    const float* degrees = (const float*)d_in[1];
    const float* W1 = (const float*)d_in[3];
    const float* b1 = (const float*)d_in[4];
    const float* W2 = (const float*)d_in[5];
    const float* b2 = (const float*)d_in[6];
    float* g   = (float*)d_ws;           // 6 * GN floats = 6.3 MB scratch
    float* out = (float*)d_out;

    grad3_kernel<<<GN / 256, 256, 0, stream>>>(fields, degrees, W1, b1, W2, b2, g);
    final_kernel<<<GN / 256, 256, 0, stream>>>(fields, degrees, W1, b1, W2, b2, g, out);
}